// Round 6
// baseline (85.699 us; speedup 1.0000x reference)
//
#include <hip/hip_runtime.h>
#include <math.h>

#define Nn 8192
#define Dd 256
#define Kk 32

// ws float layout:
// [0,        4194304)  P[k][gh][blk][d]   32*2*256*256  (16 MB partials, no atomics)
// [4194304,  4325376)  P2[k][gh][c][d]    32*2*8*256    (512 KB, level-2 partials)
// [4325376,  4333568)  Sp[blk][k]         256*32        (per-block gamma sums)
// [4333568,  4333824)  Sp2[k][c]          32*8
#define P_OFF   0
#define P2_OFF  4194304
#define SP_OFF  4325376
#define SP2_OFF 4333568

// K1: fused gamma + partial G/H. 256 blocks x 512 thr, 32 rows/block.
// LDS 68 KB -> 2 blocks/CU at 512 thr = 16 waves/CU = 50% occupancy.
__global__ __launch_bounds__(512, 4) void fused_kernel(const float* __restrict__ x,
                                                       const float* __restrict__ w,
                                                       const float* __restrict__ b,
                                                       float* __restrict__ ws) {
    __shared__ __align__(16) float uS[8192];   // w transposed [d4][k][4]  (32 KB)
    __shared__ __align__(16) float vS[8192];   // w*b transposed           (32 KB)
    __shared__ __align__(16) float gS[1024];   // gamma [r(32)][k(32)]     (4 KB)

    float* P  = ws + P_OFF;
    float* Sp = ws + SP_OFF;
    int tid = threadIdx.x;
    int blk = blockIdx.x;

    // ---- stage + transpose w, w*b into LDS (float4) ----
    {
        const float4* w4 = (const float4*)w;
        const float4* b4 = (const float4*)b;
        float4* uD = (float4*)uS;
        float4* vD = (float4*)vS;
        #pragma unroll
        for (int i = 0; i < 4; ++i) {
            int e4 = tid + i * 512;          // 0..2047 float4s
            int k  = e4 >> 6;
            int d4 = e4 & 63;
            float4 wv = w4[e4];
            float4 bv = b4[e4];
            float4 vv = {wv.x * bv.x, wv.y * bv.y, wv.z * bv.z, wv.w * bv.w};
            uD[d4 * 32 + k] = wv;
            vD[d4 * 32 + k] = vv;
        }
    }
    __syncthreads();

    // ---- gamma: 8 waves x 4 rows ----
    {
        int lane = tid & 63;
        int wave = tid >> 6;
        int k = lane & 31;
        int h = lane >> 5;
        int r0 = wave * 4;
        size_t rowbase = (size_t)blk * 32 + r0;

        const float4* uS4 = (const float4*)uS;
        const float4* vS4 = (const float4*)vS;
        const float4* xr0 = (const float4*)(x + (rowbase + 0) * Dd);
        const float4* xr1 = (const float4*)(x + (rowbase + 1) * Dd);
        const float4* xr2 = (const float4*)(x + (rowbase + 2) * Dd);
        const float4* xr3 = (const float4*)(x + (rowbase + 3) * Dd);

        float4 a0 = {0.f,0.f,0.f,0.f}, a1 = a0, a2 = a0, a3 = a0;

        #pragma unroll 4
        for (int i = 0; i < 32; ++i) {
            int ii = h * 32 + i;
            float4 u  = uS4[ii * 32 + k];
            float4 v  = vS4[ii * 32 + k];
            float4 x0 = xr0[ii];
            float4 x1 = xr1[ii];
            float4 x2 = xr2[ii];
            float4 x3 = xr3[ii];
            float y;
            y = fmaf(u.x, x0.x, v.x); a0.x = fmaf(y, y, a0.x);
            y = fmaf(u.y, x0.y, v.y); a0.y = fmaf(y, y, a0.y);
            y = fmaf(u.z, x0.z, v.z); a0.z = fmaf(y, y, a0.z);
            y = fmaf(u.w, x0.w, v.w); a0.w = fmaf(y, y, a0.w);
            y = fmaf(u.x, x1.x, v.x); a1.x = fmaf(y, y, a1.x);
            y = fmaf(u.y, x1.y, v.y); a1.y = fmaf(y, y, a1.y);
            y = fmaf(u.z, x1.z, v.z); a1.z = fmaf(y, y, a1.z);
            y = fmaf(u.w, x1.w, v.w); a1.w = fmaf(y, y, a1.w);
            y = fmaf(u.x, x2.x, v.x); a2.x = fmaf(y, y, a2.x);
            y = fmaf(u.y, x2.y, v.y); a2.y = fmaf(y, y, a2.y);
            y = fmaf(u.z, x2.z, v.z); a2.z = fmaf(y, y, a2.z);
            y = fmaf(u.w, x2.w, v.w); a2.w = fmaf(y, y, a2.w);
            y = fmaf(u.x, x3.x, v.x); a3.x = fmaf(y, y, a3.x);
            y = fmaf(u.y, x3.y, v.y); a3.y = fmaf(y, y, a3.y);
            y = fmaf(u.z, x3.z, v.z); a3.z = fmaf(y, y, a3.z);
            y = fmaf(u.w, x3.w, v.w); a3.w = fmaf(y, y, a3.w);
        }

        float s0 = (a0.x + a0.y) + (a0.z + a0.w);
        float s1 = (a1.x + a1.y) + (a1.z + a1.w);
        float s2 = (a2.x + a2.y) + (a2.z + a2.w);
        float s3 = (a3.x + a3.y) + (a3.z + a3.w);
        s0 += __shfl_xor(s0, 32);
        s1 += __shfl_xor(s1, 32);
        s2 += __shfl_xor(s2, 32);
        s3 += __shfl_xor(s3, 32);
        float y40 = -0.5f * s0, y41 = -0.5f * s1, y42 = -0.5f * s2, y43 = -0.5f * s3;

        float m0 = y40, m1 = y41, m2 = y42, m3 = y43;
        #pragma unroll
        for (int o = 16; o >= 1; o >>= 1) {
            m0 = fmaxf(m0, __shfl_xor(m0, o));
            m1 = fmaxf(m1, __shfl_xor(m1, o));
            m2 = fmaxf(m2, __shfl_xor(m2, o));
            m3 = fmaxf(m3, __shfl_xor(m3, o));
        }
        float e0 = __expf(y40 - m0), e1 = __expf(y41 - m1);
        float e2 = __expf(y42 - m2), e3 = __expf(y43 - m3);
        float t0 = e0, t1 = e1, t2 = e2, t3 = e3;
        #pragma unroll
        for (int o = 16; o >= 1; o >>= 1) {
            t0 += __shfl_xor(t0, o);
            t1 += __shfl_xor(t1, o);
            t2 += __shfl_xor(t2, o);
            t3 += __shfl_xor(t3, o);
        }
        if (h == 0) {
            gS[(r0 + 0) * 32 + k] = e0 / t0;
            gS[(r0 + 1) * 32 + k] = e1 / t1;
            gS[(r0 + 2) * 32 + k] = e2 / t2;
            gS[(r0 + 3) * 32 + k] = e3 / t3;
        }
    }
    __syncthreads();

    // ---- per-block gamma sums -> Sp[blk][k] (wave 0, lanes 0..31) ----
    if (tid < 32) {
        float s0 = 0.f, s1 = 0.f, s2 = 0.f, s3 = 0.f;
        #pragma unroll
        for (int r = 0; r < 32; r += 4) {
            s0 += gS[(r + 0) * 32 + tid];
            s1 += gS[(r + 1) * 32 + tid];
            s2 += gS[(r + 2) * 32 + tid];
            s3 += gS[(r + 3) * 32 + tid];
        }
        Sp[blk * 32 + tid] = (s0 + s1) + (s2 + s3);
    }

    // ---- accumulate: thread = (kh, d); 32 G/H accumulators ----
    {
        int kh = tid >> 8;                  // 0 or 1 -> k in [16kh, 16kh+16)
        int d  = tid & 255;
        const float* xcol = x + ((size_t)blk * 32) * Dd + d;   // warm in L1/L2
        const float4* gS4 = (const float4*)gS;

        float aG[16], aH[16];
        #pragma unroll
        for (int j = 0; j < 16; ++j) { aG[j] = 0.f; aH[j] = 0.f; }

        #pragma unroll 4
        for (int r = 0; r < 32; ++r) {
            float xv = xcol[(size_t)r * Dd];
            float xx = xv * xv;
            #pragma unroll
            for (int q = 0; q < 4; ++q) {
                float4 gv = gS4[r * 8 + kh * 4 + q];   // uniform addr -> broadcast
                aG[4*q+0] = fmaf(gv.x, xv, aG[4*q+0]); aH[4*q+0] = fmaf(gv.x, xx, aH[4*q+0]);
                aG[4*q+1] = fmaf(gv.y, xv, aG[4*q+1]); aH[4*q+1] = fmaf(gv.y, xx, aH[4*q+1]);
                aG[4*q+2] = fmaf(gv.z, xv, aG[4*q+2]); aH[4*q+2] = fmaf(gv.z, xx, aH[4*q+2]);
                aG[4*q+3] = fmaf(gv.w, xv, aG[4*q+3]); aH[4*q+3] = fmaf(gv.w, xx, aH[4*q+3]);
            }
        }

        #pragma unroll
        for (int j = 0; j < 16; ++j) {
            int k = kh * 16 + j;
            P[((size_t)(k * 2 + 0) * 256 + blk) * 256 + d] = aG[j];
            P[((size_t)(k * 2 + 1) * 256 + blk) * 256 + d] = aH[j];
        }
    }
}

// K2: 512 blocks x 256 thr; block=(k, gh, chunk c of 32 partial-blocks).
__global__ __launch_bounds__(256) void red1_kernel(float* __restrict__ ws) {
    const float* P  = ws + P_OFF;
    const float* Sp = ws + SP_OFF;
    float* P2  = ws + P2_OFF;
    float* Sp2 = ws + SP2_OFF;
    int tid = threadIdx.x;
    int k  = blockIdx.x >> 4;
    int gh = (blockIdx.x >> 3) & 1;
    int c  = blockIdx.x & 7;

    const float* p = P + ((size_t)(k * 2 + gh) * 256 + c * 32) * 256 + tid;
    float s0 = 0.f, s1 = 0.f, s2 = 0.f, s3 = 0.f;
    #pragma unroll
    for (int i = 0; i < 32; i += 4) {
        s0 += p[(size_t)(i + 0) * 256];
        s1 += p[(size_t)(i + 1) * 256];
        s2 += p[(size_t)(i + 2) * 256];
        s3 += p[(size_t)(i + 3) * 256];
    }
    P2[((size_t)(k * 2 + gh) * 8 + c) * 256 + tid] = (s0 + s1) + (s2 + s3);

    if (gh == 0 && tid == 0) {
        float t0 = 0.f, t1 = 0.f, t2 = 0.f, t3 = 0.f;
        #pragma unroll
        for (int i = 0; i < 32; i += 4) {
            t0 += Sp[(c * 32 + i + 0) * 32 + k];
            t1 += Sp[(c * 32 + i + 1) * 32 + k];
            t2 += Sp[(c * 32 + i + 2) * 32 + k];
            t3 += Sp[(c * 32 + i + 3) * 32 + k];
        }
        Sp2[k * 8 + c] = (t0 + t1) + (t2 + t3);
    }
}

// K3: 32 blocks x 256 thr; block=k, thread=d. Final sums + epilogue.
__global__ __launch_bounds__(256) void red2_kernel(const float* __restrict__ w,
                                                   const float* __restrict__ b,
                                                   const float* __restrict__ ws,
                                                   float* __restrict__ out) {
    const float* P2  = ws + P2_OFF;
    const float* Sp2 = ws + SP2_OFF;
    int k = blockIdx.x, d = threadIdx.x;

    const float* pg = P2 + (size_t)(k * 2 + 0) * 8 * 256 + d;
    const float* ph = P2 + (size_t)(k * 2 + 1) * 8 * 256 + d;
    float Gv = 0.f, Hv = 0.f, sv = 0.f;
    #pragma unroll
    for (int c = 0; c < 8; ++c) {
        Gv += pg[c * 256];
        Hv += ph[c * 256];
        sv += Sp2[k * 8 + c];
    }

    int idx = k * Dd + d;
    float wv = w[idx], bv = b[idx];
    const float invN = 1.0f / 8192.0f;
    const float c2 = 0.70710678118654752440f * invN;   // 1/(sqrt(2)*N)
    float mu = wv * (Gv + bv * sv) * invN;
    float w2 = wv * wv;
    float sg = (w2 * (Hv + 2.0f * bv * Gv + bv * bv * sv) - sv) * c2;
    out[idx] = sg;              // sigma_part
    out[Kk * Dd + idx] = mu;    // mu_part
}

extern "C" void kernel_launch(void* const* d_in, const int* in_sizes, int n_in,
                              void* d_out, int out_size, void* d_ws, size_t ws_size,
                              hipStream_t stream) {
    const float* x = (const float*)d_in[0];
    const float* w = (const float*)d_in[1];
    const float* b = (const float*)d_in[2];
    float* out = (float*)d_out;
    float* ws = (float*)d_ws;

    hipLaunchKernelGGL(fused_kernel, dim3(256), dim3(512), 0, stream, x, w, b, ws);
    hipLaunchKernelGGL(red1_kernel,  dim3(512), dim3(256), 0, stream, ws);
    hipLaunchKernelGGL(red2_kernel,  dim3(32),  dim3(256), 0, stream, w, b, ws, out);
}

// Round 7
// 83.919 us; speedup vs baseline: 1.0212x; 1.0212x over previous
//
#include <hip/hip_runtime.h>
#include <math.h>

#define Nn 8192
#define Dd 256
#define Kk 32

// ws float layout:
// [0,        4194304)  P[k][gh][blk][d]   32*2*256*256  (16 MB partials, no atomics)
// [4194304,  4325376)  P2[k][gh][c][d]    32*2*8*256    (512 KB, level-2 partials)
// [4325376,  4333568)  Sp[blk][k]         256*32        (per-block gamma sums)
#define P_OFF   0
#define P2_OFF  4194304
#define SP_OFF  4325376

// K1: fused gamma + partial G/H. 256 blocks x 1024 thr, 32 rows/block.
// 16 waves/CU = 50% occupancy. LDS ~70 KB.
__global__ __launch_bounds__(1024) void fused_kernel(const float* __restrict__ x,
                                                     const float* __restrict__ w,
                                                     const float* __restrict__ b,
                                                     float* __restrict__ ws) {
    // transposed stride 33 float4 (pad +1) -> conflict-free staging & reads
    __shared__ __align__(16) float4 uS4[64 * 33];   // ~33.8 KB
    __shared__ __align__(16) float4 vS4[64 * 33];   // ~33.8 KB
    __shared__ __align__(16) float  gS[1024];       // gamma [r(32)][k(32)] 4 KB

    float* P  = ws + P_OFF;
    float* Sp = ws + SP_OFF;
    int tid = threadIdx.x;
    int blk = blockIdx.x;

    // ---- stage + transpose w, w*b into LDS ----
    {
        const float4* w4 = (const float4*)w;
        const float4* b4 = (const float4*)b;
        #pragma unroll
        for (int i = 0; i < 2; ++i) {
            int e4 = tid + i * 1024;         // 0..2047 float4s
            int k  = e4 >> 6;                // 64 float4s per k-row
            int d4 = e4 & 63;
            float4 wv = w4[e4];
            float4 bv = b4[e4];
            float4 vv = {wv.x * bv.x, wv.y * bv.y, wv.z * bv.z, wv.w * bv.w};
            uS4[d4 * 33 + k] = wv;
            vS4[d4 * 33 + k] = vv;
        }
    }
    __syncthreads();

    // ---- gamma: 16 waves x 2 rows ----
    {
        int lane = tid & 63;
        int wave = tid >> 6;
        int k = lane & 31;
        int h = lane >> 5;
        int r0 = wave * 2;
        size_t rowbase = (size_t)blk * 32 + r0;

        const float4* xr0 = (const float4*)(x + (rowbase + 0) * Dd);
        const float4* xr1 = (const float4*)(x + (rowbase + 1) * Dd);

        float4 a0 = {0.f, 0.f, 0.f, 0.f}, a1 = a0;

        #pragma unroll 8
        for (int i = 0; i < 32; ++i) {
            int ii = h * 32 + i;
            float4 u  = uS4[ii * 33 + k];
            float4 v  = vS4[ii * 33 + k];
            float4 x0 = xr0[ii];             // broadcast within half-wave
            float4 x1 = xr1[ii];
            float y;
            y = fmaf(u.x, x0.x, v.x); a0.x = fmaf(y, y, a0.x);
            y = fmaf(u.y, x0.y, v.y); a0.y = fmaf(y, y, a0.y);
            y = fmaf(u.z, x0.z, v.z); a0.z = fmaf(y, y, a0.z);
            y = fmaf(u.w, x0.w, v.w); a0.w = fmaf(y, y, a0.w);
            y = fmaf(u.x, x1.x, v.x); a1.x = fmaf(y, y, a1.x);
            y = fmaf(u.y, x1.y, v.y); a1.y = fmaf(y, y, a1.y);
            y = fmaf(u.z, x1.z, v.z); a1.z = fmaf(y, y, a1.z);
            y = fmaf(u.w, x1.w, v.w); a1.w = fmaf(y, y, a1.w);
        }

        float s0 = (a0.x + a0.y) + (a0.z + a0.w);
        float s1 = (a1.x + a1.y) + (a1.z + a1.w);
        s0 += __shfl_xor(s0, 32);            // combine the two d-halves
        s1 += __shfl_xor(s1, 32);
        float y40 = -0.5f * s0, y41 = -0.5f * s1;

        float m0 = y40, m1 = y41;
        #pragma unroll
        for (int o = 16; o >= 1; o >>= 1) {
            m0 = fmaxf(m0, __shfl_xor(m0, o));
            m1 = fmaxf(m1, __shfl_xor(m1, o));
        }
        float e0 = __expf(y40 - m0), e1 = __expf(y41 - m1);
        float t0 = e0, t1 = e1;
        #pragma unroll
        for (int o = 16; o >= 1; o >>= 1) {
            t0 += __shfl_xor(t0, o);
            t1 += __shfl_xor(t1, o);
        }
        if (h == 0) {
            gS[(r0 + 0) * 32 + k] = e0 / t0;
            gS[(r0 + 1) * 32 + k] = e1 / t1;
        }
    }
    __syncthreads();

    // ---- per-block gamma sums -> Sp[blk][k] ----
    if (tid < 32) {
        float s0 = 0.f, s1 = 0.f, s2 = 0.f, s3 = 0.f;
        #pragma unroll
        for (int r = 0; r < 32; r += 4) {
            s0 += gS[(r + 0) * 32 + tid];
            s1 += gS[(r + 1) * 32 + tid];
            s2 += gS[(r + 2) * 32 + tid];
            s3 += gS[(r + 3) * 32 + tid];
        }
        Sp[blk * 32 + tid] = (s0 + s1) + (s2 + s3);
    }

    // ---- accumulate: thread = (kq, d); 8 G + 8 H accumulators ----
    {
        int kq = tid >> 8;                   // 0..3 -> k in [8*kq, 8*kq+8)
        int d  = tid & 255;
        const float* xcol = x + ((size_t)blk * 32) * Dd + d;   // L1/L2-warm
        const float4* gS4 = (const float4*)gS;

        float aG[8], aH[8];
        #pragma unroll
        for (int j = 0; j < 8; ++j) { aG[j] = 0.f; aH[j] = 0.f; }

        #pragma unroll 4
        for (int r = 0; r < 32; ++r) {
            float xv = xcol[(size_t)r * Dd];
            float xx = xv * xv;
            #pragma unroll
            for (int q = 0; q < 2; ++q) {
                float4 gv = gS4[r * 8 + kq * 2 + q];   // wave-uniform -> broadcast
                aG[4*q+0] = fmaf(gv.x, xv, aG[4*q+0]); aH[4*q+0] = fmaf(gv.x, xx, aH[4*q+0]);
                aG[4*q+1] = fmaf(gv.y, xv, aG[4*q+1]); aH[4*q+1] = fmaf(gv.y, xx, aH[4*q+1]);
                aG[4*q+2] = fmaf(gv.z, xv, aG[4*q+2]); aH[4*q+2] = fmaf(gv.z, xx, aH[4*q+2]);
                aG[4*q+3] = fmaf(gv.w, xv, aG[4*q+3]); aH[4*q+3] = fmaf(gv.w, xx, aH[4*q+3]);
            }
        }

        #pragma unroll
        for (int j = 0; j < 8; ++j) {
            int k = kq * 8 + j;
            P[((size_t)(k * 2 + 0) * 256 + blk) * 256 + d] = aG[j];
            P[((size_t)(k * 2 + 1) * 256 + blk) * 256 + d] = aH[j];
        }
    }
}

// K2: 512 blocks x 256 thr; block=(k, gh, chunk c of 32 partial-slabs).
__global__ __launch_bounds__(256) void red1_kernel(float* __restrict__ ws) {
    const float* P = ws + P_OFF;
    float* P2 = ws + P2_OFF;
    int tid = threadIdx.x;
    int k  = blockIdx.x >> 4;
    int gh = (blockIdx.x >> 3) & 1;
    int c  = blockIdx.x & 7;

    const float* p = P + ((size_t)(k * 2 + gh) * 256 + c * 32) * 256 + tid;
    float s0 = 0.f, s1 = 0.f, s2 = 0.f, s3 = 0.f;
    #pragma unroll
    for (int i = 0; i < 32; i += 4) {
        s0 += p[(size_t)(i + 0) * 256];
        s1 += p[(size_t)(i + 1) * 256];
        s2 += p[(size_t)(i + 2) * 256];
        s3 += p[(size_t)(i + 3) * 256];
    }
    P2[((size_t)(k * 2 + gh) * 8 + c) * 256 + tid] = (s0 + s1) + (s2 + s3);
}

// K3: 32 blocks x 256 thr; block=k, thread=d. Final sums + S + epilogue.
__global__ __launch_bounds__(256) void red2_kernel(const float* __restrict__ w,
                                                   const float* __restrict__ b,
                                                   const float* __restrict__ ws,
                                                   float* __restrict__ out) {
    const float* P2 = ws + P2_OFF;
    const float* Sp = ws + SP_OFF;
    __shared__ float sred[4];
    int k = blockIdx.x, d = threadIdx.x;

    // ---- S[k] = sum over 256 blocks, thread-parallel + shuffle reduce ----
    float sv_part = Sp[d * 32 + k];
    #pragma unroll
    for (int o = 32; o >= 1; o >>= 1) sv_part += __shfl_xor(sv_part, o);
    if ((d & 63) == 0) sred[d >> 6] = sv_part;
    __syncthreads();
    float sv = (sred[0] + sred[1]) + (sred[2] + sred[3]);

    const float* pg = P2 + (size_t)(k * 2 + 0) * 8 * 256 + d;
    const float* ph = P2 + (size_t)(k * 2 + 1) * 8 * 256 + d;
    float Gv = 0.f, Hv = 0.f;
    #pragma unroll
    for (int c = 0; c < 8; ++c) {
        Gv += pg[c * 256];
        Hv += ph[c * 256];
    }

    int idx = k * Dd + d;
    float wv = w[idx], bv = b[idx];
    const float invN = 1.0f / 8192.0f;
    const float c2 = 0.70710678118654752440f * invN;   // 1/(sqrt(2)*N)
    float mu = wv * (Gv + bv * sv) * invN;
    float w2 = wv * wv;
    float sg = (w2 * (Hv + 2.0f * bv * Gv + bv * bv * sv) - sv) * c2;
    out[idx] = sg;              // sigma_part
    out[Kk * Dd + idx] = mu;    // mu_part
}

extern "C" void kernel_launch(void* const* d_in, const int* in_sizes, int n_in,
                              void* d_out, int out_size, void* d_ws, size_t ws_size,
                              hipStream_t stream) {
    const float* x = (const float*)d_in[0];
    const float* w = (const float*)d_in[1];
    const float* b = (const float*)d_in[2];
    float* out = (float*)d_out;
    float* ws = (float*)d_ws;

    hipLaunchKernelGGL(fused_kernel, dim3(256), dim3(1024), 0, stream, x, w, b, ws);
    hipLaunchKernelGGL(red1_kernel,  dim3(512), dim3(256),  0, stream, ws);
    hipLaunchKernelGGL(red2_kernel,  dim3(32),  dim3(256),  0, stream, w, b, ws, out);
}